// Round 1
// baseline (712.960 us; speedup 1.0000x reference)
//
#include <hip/hip_runtime.h>
#include <cstdint>

#define NPRI 33600
#define NGT  256
#define NCLS 80
#define KTOP 13
#define INF_F 1.0e8f
#define EPS_F 1e-7f
#define LOG2_10 3.3219280948873623f

typedef unsigned long long u64;

__device__ __forceinline__ int get_label(const void* p, int j, int is64) {
    if (is64) return (int)((const long long*)p)[j];
    return ((const int*)p)[j];
}

// Detect int64 vs int32 storage of gt_labels. Reads only first 1024 bytes,
// which is in-bounds for both layouts (int32: 256*4=1024B exactly).
__global__ void k_detect(const void* labels, int* flag) {
    int tid = threadIdx.x;
    __shared__ int bad;
    if (tid == 0) bad = 0;
    __syncthreads();
    long long v = ((const long long*)labels)[tid];   // tid in [0,128)
    if (v < 0 || v >= NCLS) bad = 1;                 // benign race
    __syncthreads();
    if (tid == 0) *flag = bad ? 0 : 1;               // 1 => int64 layout
}

__global__ void k_init(int* count, int* firstgt) {
    int i = blockIdx.x * blockDim.x + threadIdx.x;
    if (i < NPRI) { count[i] = 0; firstgt[i] = NGT; }
}

__global__ __launch_bounds__(256) void k_valid(const float* priors, const float* gt, int* valid) {
    __shared__ float4 gbox[NGT];
    __shared__ int    gpad[NGT];
    int tid = threadIdx.x;
    {
        float4 b = ((const float4*)gt)[tid];
        gbox[tid] = b;
        gpad[tid] = ((b.x + b.y + b.z + b.w) > 0.0f) ? 1 : 0;
    }
    __syncthreads();
    int i = blockIdx.x * blockDim.x + tid;
    if (i >= NPRI) return;
    float4 pr = ((const float4*)priors)[i];
    float px = pr.x, py = pr.y;
    int v = 0;
    for (int j = 0; j < NGT; ++j) {
        float4 b = gbox[j];
        float m = fminf(fminf(px - b.x, py - b.y), fminf(b.z - px, b.w - py));
        if (m > 0.0f && gpad[j]) { v = 1; break; }
    }
    valid[i] = v;
}

__device__ __forceinline__ u64 wave_min_u64(u64 v) {
    #pragma unroll
    for (int off = 32; off > 0; off >>= 1) {
        u64 o = __shfl_down(v, off, 64);
        v = (o < v) ? o : v;
    }
    return v;
}
__device__ __forceinline__ u64 wave_max_u64(u64 v) {
    #pragma unroll
    for (int off = 32; off > 0; off >>= 1) {
        u64 o = __shfl_down(v, off, 64);
        v = (o > v) ? o : v;
    }
    return v;
}

// One block (256 threads) per GT column: top-13 min-cost candidates and
// top-13 IoU sum -> dynamic_ks -> scatter count/firstgt.
__global__ __launch_bounds__(256) void k_select(
        const float* __restrict__ scores, const float* __restrict__ priors,
        const float* __restrict__ pboxes, const float* __restrict__ gt,
        const void* labels, const int* flag, const int* __restrict__ valid,
        int* count, int* firstgt) {
    const int tid = threadIdx.x;
    const int j = blockIdx.x;
    const int is64 = *flag;

    const float4 gb = ((const float4*)gt)[j];
    const float gx1 = gb.x, gy1 = gb.y, gx2 = gb.z, gy2 = gb.w;
    const float areag = (gx2 - gx1) * (gy2 - gy1);
    const float gcx = (gx1 + gx2) * 0.5f, gcy = (gy1 + gy2) * 0.5f;
    const int lab = get_label(labels, j, is64);

    u64 lc[KTOP];   // min-cost list, ascending (keys: cost_bits<<32 | idx)
    u64 li[KTOP];   // max-iou  list, ascending (keys: iou_bits<<32 | idx)
    #pragma unroll
    for (int s = 0; s < KTOP; ++s) { lc[s] = ~0ull; li[s] = 0ull; }

    for (int i = tid; i < NPRI; i += 256) {
        float4 pb = ((const float4*)pboxes)[i];
        float areap = (pb.z - pb.x) * (pb.w - pb.y);
        float iw = fmaxf(fminf(pb.z, gx2) - fmaxf(pb.x, gx1), 0.0f);
        float ih = fmaxf(fminf(pb.w, gy2) - fmaxf(pb.y, gy1), 0.0f);
        float inter = iw * ih;
        float iou = inter / fmaxf(areap + areag - inter, 1e-6f);

        u64 ik = (((u64)__float_as_uint(iou)) << 32) | (unsigned)i;
        if (ik > li[0]) {
            li[0] = ik;
            #pragma unroll
            for (int s = 0; s < KTOP - 1; ++s)
                if (li[s] > li[s + 1]) { u64 t = li[s]; li[s] = li[s + 1]; li[s + 1] = t; }
        }

        float cost;
        if (valid[i]) {
            float4 pr = ((const float4*)priors)[i];
            float dx = pr.x - gcx, dy = pr.y - gcy;
            float dist = sqrtf(dx * dx + dy * dy) / pr.z;
            float soft = exp2f((dist - 3.0f) * LOG2_10);
            float l = scores[i * NCLS + lab];
            float sig = 1.0f / (1.0f + __expf(-l) * 0.0f + expf(-l)); // keep libm expf
            sig = 1.0f / (1.0f + expf(-l));
            float dd = iou - sig;
            float bce = fmaxf(l, 0.0f) - l * iou + log1pf(expf(-fabsf(l)));
            float iouc = -logf(iou + EPS_F) * 3.0f;
            cost = bce * (dd * dd) + iouc + soft;
        } else {
            cost = INF_F;
        }
        u64 ck = (((u64)__float_as_uint(cost)) << 32) | (unsigned)i;
        if (ck < lc[KTOP - 1]) {
            lc[KTOP - 1] = ck;
            #pragma unroll
            for (int s = KTOP - 1; s > 0; --s)
                if (lc[s] < lc[s - 1]) { u64 t = lc[s]; lc[s] = lc[s - 1]; lc[s - 1] = t; }
        }
    }

    __shared__ u64 red4[4];
    __shared__ u64 cand[KTOP];
    __shared__ float tiou[KTOP];
    __shared__ int sks;
    const int wid = tid >> 6;

    // ---- min-cost merge: 13 rounds ----
    {
        int p = 0;
        for (int r = 0; r < KTOP; ++r) {
            u64 cur = ~0ull;
            #pragma unroll
            for (int s = 0; s < KTOP; ++s) if (s == p) cur = lc[s];
            u64 wm = wave_min_u64(cur);
            if ((tid & 63) == 0) red4[wid] = wm;
            __syncthreads();
            u64 w = red4[0];
            #pragma unroll
            for (int q = 1; q < 4; ++q) w = (red4[q] < w) ? red4[q] : w;
            if (cur == w) p++;                 // unique (idx in key)
            if (tid == 0) cand[r] = w;
            __syncthreads();
        }
    }
    // ---- max-iou merge: 13 rounds ----
    {
        int p = 0;
        for (int r = 0; r < KTOP; ++r) {
            u64 cur = 0ull;
            #pragma unroll
            for (int s = 0; s < KTOP; ++s) if (s == p) cur = li[KTOP - 1 - s]; // descending
            u64 wm = wave_max_u64(cur);
            if ((tid & 63) == 0) red4[wid] = wm;
            __syncthreads();
            u64 w = red4[0];
            #pragma unroll
            for (int q = 1; q < 4; ++q) w = (red4[q] > w) ? red4[q] : w;
            if (cur == w && w != 0ull) p++;
            if (tid == 0) tiou[r] = __uint_as_float((unsigned)(w >> 32));
            __syncthreads();
        }
    }

    if (tid == 0) {
        float s = 0.0f;
        for (int r = 0; r < KTOP; ++r) s += tiou[r];  // descending-order sum
        int ks = (int)s;                               // trunc toward zero
        if (ks < 1) ks = 1;
        sks = ks;
    }
    __syncthreads();
    if (tid < KTOP && tid < sks) {
        int idx = (int)(unsigned)(cand[tid] & 0xFFFFFFFFull);
        atomicAdd(&count[idx], 1);
        atomicMin(&firstgt[idx], j);
    }
}

__global__ __launch_bounds__(256) void k_assign(
        const float* __restrict__ scores, const float* __restrict__ priors,
        const float* __restrict__ pboxes, const float* __restrict__ gt,
        const void* labels, const int* flag, const int* __restrict__ valid,
        const int* __restrict__ count, const int* __restrict__ firstgt,
        float* __restrict__ out) {
    __shared__ float4 gbox[NGT];
    __shared__ int glab[NGT];
    __shared__ float gcxs[NGT], gcys[NGT], gareas[NGT];
    int tid = threadIdx.x;
    int is64 = *flag;
    {
        float4 b = ((const float4*)gt)[tid];
        gbox[tid] = b;
        glab[tid] = get_label(labels, tid, is64);
        gcxs[tid] = (b.x + b.z) * 0.5f;
        gcys[tid] = (b.y + b.w) * 0.5f;
        gareas[tid] = (b.z - b.x) * (b.w - b.y);
    }
    __syncthreads();
    int i = blockIdx.x * 256 + tid;
    if (i >= NPRI) return;
    int v = valid[i];
    int c = count[i];
    float o0 = 0.0f, o1 = -INF_F, o2 = -1.0f;
    if (v && c > 0) {
        float4 pb = ((const float4*)pboxes)[i];
        float areap = (pb.z - pb.x) * (pb.w - pb.y);
        if (c == 1) {
            int j = firstgt[i];
            float4 g = gbox[j];
            float iw = fmaxf(fminf(pb.z, g.z) - fmaxf(pb.x, g.x), 0.0f);
            float ih = fmaxf(fminf(pb.w, g.w) - fmaxf(pb.y, g.y), 0.0f);
            float inter = iw * ih;
            float iou = inter / fmaxf(areap + gareas[j] - inter, 1e-6f);
            o0 = (float)(j + 1); o1 = iou; o2 = (float)glab[j];
        } else {
            float4 pr = ((const float4*)priors)[i];
            float best = __uint_as_float(0x7f800000u); // +inf
            int jmin = 0; float biou = 0.0f;
            for (int j = 0; j < NGT; ++j) {
                float4 g = gbox[j];
                float iw = fmaxf(fminf(pb.z, g.z) - fmaxf(pb.x, g.x), 0.0f);
                float ih = fmaxf(fminf(pb.w, g.w) - fmaxf(pb.y, g.y), 0.0f);
                float inter = iw * ih;
                float iou = inter / fmaxf(areap + gareas[j] - inter, 1e-6f);
                float dx = pr.x - gcxs[j], dy = pr.y - gcys[j];
                float dist = sqrtf(dx * dx + dy * dy) / pr.z;
                float soft = exp2f((dist - 3.0f) * LOG2_10);
                float l = scores[i * NCLS + glab[j]];
                float sig = 1.0f / (1.0f + expf(-l));
                float dd = iou - sig;
                float bce = fmaxf(l, 0.0f) - l * iou + log1pf(expf(-fabsf(l)));
                float cost = bce * (dd * dd) + (-logf(iou + EPS_F) * 3.0f) + soft;
                if (cost < best) { best = cost; jmin = j; biou = iou; }  // first-min
            }
            o0 = (float)(jmin + 1); o1 = biou; o2 = (float)glab[jmin];
        }
    }
    out[i] = o0;
    out[NPRI + i] = o1;
    out[2 * NPRI + i] = o2;
}

extern "C" void kernel_launch(void* const* d_in, const int* in_sizes, int n_in,
                              void* d_out, int out_size, void* d_ws, size_t ws_size,
                              hipStream_t stream) {
    const float* scores = (const float*)d_in[0];
    const float* priors = (const float*)d_in[1];
    const float* pboxes = (const float*)d_in[2];
    const float* gt     = (const float*)d_in[3];
    const void*  labels = d_in[4];
    float* out = (float*)d_out;

    char* ws = (char*)d_ws;
    int* flag    = (int*)ws;                                   // 64 B slot
    int* count   = (int*)(ws + 64);                            // N ints
    int* firstgt = (int*)(ws + 64 + (size_t)NPRI * 4);         // N ints
    int* valid   = (int*)(ws + 64 + (size_t)NPRI * 8);         // N ints

    hipLaunchKernelGGL(k_detect, dim3(1), dim3(128), 0, stream, labels, flag);
    hipLaunchKernelGGL(k_init, dim3((NPRI + 255) / 256), dim3(256), 0, stream, count, firstgt);
    hipLaunchKernelGGL(k_valid, dim3((NPRI + 255) / 256), dim3(256), 0, stream, priors, gt, valid);
    hipLaunchKernelGGL(k_select, dim3(NGT), dim3(256), 0, stream,
                       scores, priors, pboxes, gt, labels, flag, valid, count, firstgt);
    hipLaunchKernelGGL(k_assign, dim3((NPRI + 255) / 256), dim3(256), 0, stream,
                       scores, priors, pboxes, gt, labels, flag, valid, count, firstgt, out);
}

// Round 2
// 246.605 us; speedup vs baseline: 2.8911x; 2.8911x over previous
//
#include <hip/hip_runtime.h>
#include <cstdint>

#define NPRI 33600
#define NGT  256
#define NCLS 80
#define KTOP 13
#define INF_F 1.0e8f
#define EPS_F 1e-7f
#define LOG2_10 3.3219280948873623f

typedef unsigned long long u64;

__device__ __forceinline__ int get_label(const void* p, int j, int is64) {
    if (is64) return (int)((const long long*)p)[j];
    return ((const int*)p)[j];
}

// Detect int64 vs int32 storage of gt_labels. Reads only first 1024 bytes,
// in-bounds for both layouts (int32: 256*4=1024B exactly).
__global__ void k_detect(const void* labels, int* flag) {
    int tid = threadIdx.x;
    __shared__ int bad;
    if (tid == 0) bad = 0;
    __syncthreads();
    long long v = ((const long long*)labels)[tid];   // tid in [0,128)
    if (v < 0 || v >= NCLS) bad = 1;                 // benign race
    __syncthreads();
    if (tid == 0) *flag = bad ? 0 : 1;               // 1 => int64 layout
}

__global__ void k_init(int* count, int* firstgt, int* nmulti) {
    int i = blockIdx.x * blockDim.x + threadIdx.x;
    if (i < NPRI) { count[i] = 0; firstgt[i] = NGT; }
    if (i == 0) *nmulti = 0;
}

// scores[i][c] (row-major, NCLS=80) -> scoresT[c][i]
__global__ __launch_bounds__(256) void k_transpose(const float* __restrict__ scores,
                                                   float* __restrict__ scoresT) {
    __shared__ float tile[32][81];
    const int base_i = blockIdx.x * 32;
    const int tid = threadIdx.x;
    for (int k = tid; k < 32 * NCLS; k += 256) {
        int ip = k / NCLS, c = k - ip * NCLS;
        tile[ip][c] = scores[(size_t)(base_i + ip) * NCLS + c];  // coalesced read
    }
    __syncthreads();
    for (int k = tid; k < 32 * NCLS; k += 256) {
        int c = k >> 5, ip = k & 31;
        scoresT[(size_t)c * NPRI + base_i + ip] = tile[ip][c];   // coalesced write
    }
}

__global__ __launch_bounds__(256) void k_valid(const float* priors, const float* gt, int* valid) {
    __shared__ float4 gbox[NGT];
    __shared__ int    gpad[NGT];
    int tid = threadIdx.x;
    {
        float4 b = ((const float4*)gt)[tid];
        gbox[tid] = b;
        gpad[tid] = ((b.x + b.y + b.z + b.w) > 0.0f) ? 1 : 0;
    }
    __syncthreads();
    int i = blockIdx.x * blockDim.x + tid;
    if (i >= NPRI) return;
    float4 pr = ((const float4*)priors)[i];
    float px = pr.x, py = pr.y;
    int v = 0;
    for (int j = 0; j < NGT; ++j) {
        float4 b = gbox[j];
        float m = fminf(fminf(px - b.x, py - b.y), fminf(b.z - px, b.w - py));
        if (m > 0.0f && gpad[j]) { v = 1; break; }
    }
    valid[i] = v;
}

__device__ __forceinline__ u64 wave_red_minmax(u64 vmin, u64 vmax, u64* outmax) {
    #pragma unroll
    for (int off = 32; off > 0; off >>= 1) {
        u64 a = __shfl_down(vmin, off, 64);
        u64 b = __shfl_down(vmax, off, 64);
        vmin = (a < vmin) ? a : vmin;
        vmax = (b > vmax) ? b : vmax;
    }
    *outmax = vmax;
    return vmin;
}

// One block (1024 threads) per GT column: top-13 min-cost candidates and
// top-13 IoU sum -> dynamic_ks -> scatter count/firstgt.
#define SEL_T 1024
#define SEL_W (SEL_T / 64)
__global__ __launch_bounds__(SEL_T) void k_select(
        const float* __restrict__ sc, int rs, int cs,
        const float* __restrict__ priors,
        const float* __restrict__ pboxes, const float* __restrict__ gt,
        const void* labels, const int* flag, const int* __restrict__ valid,
        int* count, int* firstgt) {
    const int tid = threadIdx.x;
    const int j = blockIdx.x;
    const int is64 = *flag;

    const float4 gb = ((const float4*)gt)[j];
    const float gx1 = gb.x, gy1 = gb.y, gx2 = gb.z, gy2 = gb.w;
    const float areag = (gx2 - gx1) * (gy2 - gy1);
    const float gcx = (gx1 + gx2) * 0.5f, gcy = (gy1 + gy2) * 0.5f;
    const int lab = get_label(labels, j, is64);
    const float* scol = sc + (size_t)lab * cs;   // element i at scol[i*rs]

    u64 lc[KTOP];   // min-cost list, ascending (keys: cost_bits<<32 | idx)
    u64 li[KTOP];   // max-iou  list, ascending (keys: iou_bits<<32 | idx)
    #pragma unroll
    for (int s = 0; s < KTOP; ++s) { lc[s] = ~0ull; li[s] = 0ull; }

    for (int i = tid; i < NPRI; i += SEL_T) {
        float4 pb = ((const float4*)pboxes)[i];
        float areap = (pb.z - pb.x) * (pb.w - pb.y);
        float iw = fmaxf(fminf(pb.z, gx2) - fmaxf(pb.x, gx1), 0.0f);
        float ih = fmaxf(fminf(pb.w, gy2) - fmaxf(pb.y, gy1), 0.0f);
        float inter = iw * ih;
        float iou = inter / fmaxf(areap + areag - inter, 1e-6f);

        u64 ik = (((u64)__float_as_uint(iou)) << 32) | (unsigned)i;
        if (ik > li[0]) {
            li[0] = ik;
            #pragma unroll
            for (int s = 0; s < KTOP - 1; ++s)
                if (li[s] > li[s + 1]) { u64 t = li[s]; li[s] = li[s + 1]; li[s + 1] = t; }
        }

        float cost;
        if (valid[i]) {
            float4 pr = ((const float4*)priors)[i];
            float dx = pr.x - gcx, dy = pr.y - gcy;
            float dist = sqrtf(dx * dx + dy * dy) / pr.z;
            float soft = exp2f((dist - 3.0f) * LOG2_10);
            float l = scol[(size_t)i * rs];
            float sig = 1.0f / (1.0f + expf(-l));
            float dd = iou - sig;
            float bce = fmaxf(l, 0.0f) - l * iou + log1pf(expf(-fabsf(l)));
            float iouc = -logf(iou + EPS_F) * 3.0f;
            cost = bce * (dd * dd) + iouc + soft;
        } else {
            cost = INF_F;
        }
        u64 ck = (((u64)__float_as_uint(cost)) << 32) | (unsigned)i;
        if (ck < lc[KTOP - 1]) {
            lc[KTOP - 1] = ck;
            #pragma unroll
            for (int s = KTOP - 1; s > 0; --s)
                if (lc[s] < lc[s - 1]) { u64 t = lc[s]; lc[s] = lc[s - 1]; lc[s - 1] = t; }
        }
    }

    __shared__ u64 redc[SEL_W];
    __shared__ u64 redi[SEL_W];
    __shared__ u64 cand[KTOP];
    __shared__ float tiou[KTOP];
    __shared__ int sks;
    const int wid = tid >> 6;

    // ---- fused min-cost / max-iou merge: 13 rounds ----
    int pc = 0, pi = 0;
    for (int r = 0; r < KTOP; ++r) {
        u64 curc = ~0ull, curi = 0ull;
        #pragma unroll
        for (int s = 0; s < KTOP; ++s) {
            if (s == pc) curc = lc[s];
            if (s == pi) curi = li[KTOP - 1 - s];   // descending
        }
        u64 wmax;
        u64 wmin = wave_red_minmax(curc, curi, &wmax);
        if ((tid & 63) == 0) { redc[wid] = wmin; redi[wid] = wmax; }
        __syncthreads();
        u64 bc = redc[0], bi = redi[0];
        #pragma unroll
        for (int q = 1; q < SEL_W; ++q) {
            bc = (redc[q] < bc) ? redc[q] : bc;
            bi = (redi[q] > bi) ? redi[q] : bi;
        }
        if (curc == bc) pc++;                 // unique (idx in key)
        if (curi == bi && bi != 0ull) pi++;
        if (tid == 0) { cand[r] = bc; tiou[r] = __uint_as_float((unsigned)(bi >> 32)); }
        __syncthreads();
    }

    if (tid == 0) {
        float s = 0.0f;
        for (int r = 0; r < KTOP; ++r) s += tiou[r];  // descending-order sum
        int ks = (int)s;                               // trunc toward zero
        if (ks < 1) ks = 1;
        sks = ks;
    }
    __syncthreads();
    if (tid < KTOP && tid < sks) {
        int idx = (int)(unsigned)(cand[tid] & 0xFFFFFFFFull);
        atomicAdd(&count[idx], 1);
        atomicMin(&firstgt[idx], j);
    }
}

// Per-prior finalize; count>1 priors get appended to a worklist for k_multi.
__global__ __launch_bounds__(256) void k_assign(
        const float* __restrict__ pboxes, const float* __restrict__ gt,
        const void* labels, const int* flag, const int* __restrict__ valid,
        const int* __restrict__ count, const int* __restrict__ firstgt,
        int* nmulti, int* mlist, float* __restrict__ out) {
    __shared__ float4 gbox[NGT];
    __shared__ int glab[NGT];
    __shared__ float gareas[NGT];
    int tid = threadIdx.x;
    int is64 = *flag;
    {
        float4 b = ((const float4*)gt)[tid];
        gbox[tid] = b;
        glab[tid] = get_label(labels, tid, is64);
        gareas[tid] = (b.z - b.x) * (b.w - b.y);
    }
    __syncthreads();
    int i = blockIdx.x * 256 + tid;
    if (i >= NPRI) return;
    int v = valid[i];
    int c = count[i];
    float o0 = 0.0f, o1 = -INF_F, o2 = -1.0f;
    if (v && c == 1) {
        int j = firstgt[i];
        float4 pb = ((const float4*)pboxes)[i];
        float areap = (pb.z - pb.x) * (pb.w - pb.y);
        float4 g = gbox[j];
        float iw = fmaxf(fminf(pb.z, g.z) - fmaxf(pb.x, g.x), 0.0f);
        float ih = fmaxf(fminf(pb.w, g.w) - fmaxf(pb.y, g.y), 0.0f);
        float inter = iw * ih;
        float iou = inter / fmaxf(areap + gareas[j] - inter, 1e-6f);
        o0 = (float)(j + 1); o1 = iou; o2 = (float)glab[j];
    } else if (v && c > 1) {
        int pos = atomicAdd(nmulti, 1);
        mlist[pos] = i;
        // outputs written by k_multi
    }
    out[i] = o0;
    out[NPRI + i] = o1;
    out[2 * NPRI + i] = o2;
}

// One block per multi prior (grid-stride over worklist): 256 threads = 256 GTs,
// block argmin on packed (cost_bits<<32|j) -> first-occurrence min like jnp.argmin.
__global__ __launch_bounds__(256) void k_multi(
        const float* __restrict__ sc, int rs, int cs,
        const float* __restrict__ priors,
        const float* __restrict__ pboxes, const float* __restrict__ gt,
        const void* labels, const int* flag,
        const int* __restrict__ nmulti, const int* __restrict__ mlist,
        float* __restrict__ out) {
    __shared__ float4 gbox[NGT];
    __shared__ int glab[NGT];
    __shared__ float gcxs[NGT], gcys[NGT], gareas[NGT];
    __shared__ u64 red4[4];
    const int tid = threadIdx.x;
    const int is64 = *flag;
    {
        float4 b = ((const float4*)gt)[tid];
        gbox[tid] = b;
        glab[tid] = get_label(labels, tid, is64);
        gcxs[tid] = (b.x + b.z) * 0.5f;
        gcys[tid] = (b.y + b.w) * 0.5f;
        gareas[tid] = (b.z - b.x) * (b.w - b.y);
    }
    __syncthreads();
    const int nm = *nmulti;
    const int j = tid;   // one thread per GT
    for (int m = blockIdx.x; m < nm; m += gridDim.x) {
        const int i = mlist[m];
        float4 pb = ((const float4*)pboxes)[i];
        float areap = (pb.z - pb.x) * (pb.w - pb.y);
        float4 pr = ((const float4*)priors)[i];

        float4 g = gbox[j];
        float iw = fmaxf(fminf(pb.z, g.z) - fmaxf(pb.x, g.x), 0.0f);
        float ih = fmaxf(fminf(pb.w, g.w) - fmaxf(pb.y, g.y), 0.0f);
        float inter = iw * ih;
        float iou = inter / fmaxf(areap + gareas[j] - inter, 1e-6f);
        float dx = pr.x - gcxs[j], dy = pr.y - gcys[j];
        float dist = sqrtf(dx * dx + dy * dy) / pr.z;
        float soft = exp2f((dist - 3.0f) * LOG2_10);
        float l = sc[(size_t)i * rs + (size_t)glab[j] * cs];
        float sig = 1.0f / (1.0f + expf(-l));
        float dd = iou - sig;
        float bce = fmaxf(l, 0.0f) - l * iou + log1pf(expf(-fabsf(l)));
        float cost = bce * (dd * dd) + (-logf(iou + EPS_F) * 3.0f) + soft;

        u64 key = (((u64)__float_as_uint(cost)) << 32) | (unsigned)j;
        u64 v = key;
        #pragma unroll
        for (int off = 32; off > 0; off >>= 1) {
            u64 o = __shfl_down(v, off, 64);
            v = (o < v) ? o : v;
        }
        if ((tid & 63) == 0) red4[tid >> 6] = v;
        __syncthreads();
        u64 best = red4[0];
        #pragma unroll
        for (int q = 1; q < 4; ++q) best = (red4[q] < best) ? red4[q] : best;
        if (key == best) {   // exactly one thread (j in key)
            out[i] = (float)(j + 1);
            out[NPRI + i] = iou;
            out[2 * NPRI + i] = (float)glab[j];
        }
        __syncthreads();
    }
}

extern "C" void kernel_launch(void* const* d_in, const int* in_sizes, int n_in,
                              void* d_out, int out_size, void* d_ws, size_t ws_size,
                              hipStream_t stream) {
    const float* scores = (const float*)d_in[0];
    const float* priors = (const float*)d_in[1];
    const float* pboxes = (const float*)d_in[2];
    const float* gt     = (const float*)d_in[3];
    const void*  labels = d_in[4];
    float* out = (float*)d_out;

    char* ws = (char*)d_ws;
    int*   flag    = (int*)ws;                                     // 64 B slot
    int*   nmulti  = (int*)(ws + 64);                              // 64 B slot
    int*   count   = (int*)(ws + 128);
    int*   firstgt = (int*)(ws + 128 + (size_t)NPRI * 4);
    int*   valid   = (int*)(ws + 128 + (size_t)NPRI * 8);
    int*   mlist   = (int*)(ws + 128 + (size_t)NPRI * 12);         // 16 KiB
    float* scoresT = (float*)(ws + 128 + (size_t)NPRI * 12 + 16384 + 192); // 256B-ish aligned
    const size_t need_T = 128 + (size_t)NPRI * 12 + 16384 + 192 + (size_t)NPRI * NCLS * 4;
    const bool useT = (ws_size >= need_T);

    hipLaunchKernelGGL(k_detect, dim3(1), dim3(128), 0, stream, labels, flag);
    hipLaunchKernelGGL(k_init, dim3((NPRI + 255) / 256), dim3(256), 0, stream, count, firstgt, nmulti);
    hipLaunchKernelGGL(k_valid, dim3((NPRI + 255) / 256), dim3(256), 0, stream, priors, gt, valid);

    const float* sc = scores; int rs = NCLS, cs = 1;
    if (useT) {
        hipLaunchKernelGGL(k_transpose, dim3(NPRI / 32), dim3(256), 0, stream, scores, scoresT);
        sc = scoresT; rs = 1; cs = NPRI;
    }
    hipLaunchKernelGGL(k_select, dim3(NGT), dim3(SEL_T), 0, stream,
                       sc, rs, cs, priors, pboxes, gt, labels, flag, valid, count, firstgt);
    hipLaunchKernelGGL(k_assign, dim3((NPRI + 255) / 256), dim3(256), 0, stream,
                       pboxes, gt, labels, flag, valid, count, firstgt, nmulti, mlist, out);
    hipLaunchKernelGGL(k_multi, dim3(128), dim3(256), 0, stream,
                       sc, rs, cs, priors, pboxes, gt, labels, flag, nmulti, mlist, out);
}